// Round 4
// baseline (375.309 us; speedup 1.0000x reference)
//
#include <hip/hip_runtime.h>
#include <hip/hip_fp16.h>

#define FD 128    // hidden feature dim
#define OD 64     // output dim
#define RN 256    // nodes per region (id >> 8)
#define CHUNKS 256
#define NRMAX 1024
#define FC 32     // feature-chunk width (table slice = N*FC*2B = 3.2MB, fits 4MB per-XCD L2)

typedef _Float16 f16x8 __attribute__((ext_vector_type(8)));
typedef float    f32x4 __attribute__((ext_vector_type(4)));
typedef unsigned u32x2 __attribute__((ext_vector_type(2)));

// ---------------- misc ----------------

// Xs(half, chunked [4][N][32]) = r_out (row) * X ; one float4 -> 4 halves per thread
__global__ void prescale_kernel(const float* __restrict__ X, const float* __restrict__ r_out,
                                __half* __restrict__ Xs, int n4, int N) {
    int i = blockIdx.x * 256 + threadIdx.x;
    if (i >= n4) return;
    int v = i >> 5;                    // 32 float4 per 128-float row
    int fq = i & 31;                   // float4 index within row (features 4fq..4fq+3)
    float r = r_out[v];
    float4 t = ((const float4*)X)[i];
    __half2 h0 = __floats2half2_rn(t.x * r, t.y * r);
    __half2 h1 = __floats2half2_rn(t.z * r, t.w * r);
    int c  = fq >> 3;                  // feature chunk (32 features per chunk)
    int w0 = (fq & 7) * 4;             // feature offset within chunk
    __half2* p = (__half2*)(Xs + ((size_t)c * N + v) * FC + w0);
    p[0] = h0;
    p[1] = h1;
}

// ---------------- pass 1: dual histograms by region (dst>>8 and src>>8) ----------------
// hist layout TRANSPOSED: hist_g[region * CHUNKS + chunk] so the scan kernel streams.

__global__ __launch_bounds__(1024) void region_hist_kernel(const int* __restrict__ src,
                                                           const int* __restrict__ dst,
                                                           int* __restrict__ hist_g,
                                                           int* __restrict__ hist_gs,
                                                           int E, int NR, int CS) {
    __shared__ int hist[NRMAX];
    __shared__ int hist_s[NRMAX];
    int c = blockIdx.x;
    for (int t = threadIdx.x; t < NR; t += 1024) { hist[t] = 0; hist_s[t] = 0; }
    __syncthreads();
    int e0 = c * CS, e1 = min(e0 + CS, E);
    int nv = (e1 - e0) & ~3;
    for (int e = e0 + threadIdx.x * 4; e < e0 + nv; e += 4096) {
        int4 d = *(const int4*)(dst + e);
        int4 s = *(const int4*)(src + e);
        atomicAdd(&hist[d.x >> 8], 1);
        atomicAdd(&hist[d.y >> 8], 1);
        atomicAdd(&hist[d.z >> 8], 1);
        atomicAdd(&hist[d.w >> 8], 1);
        atomicAdd(&hist_s[s.x >> 8], 1);
        atomicAdd(&hist_s[s.y >> 8], 1);
        atomicAdd(&hist_s[s.z >> 8], 1);
        atomicAdd(&hist_s[s.w >> 8], 1);
    }
    for (int e = e0 + nv + threadIdx.x; e < e1; e += 1024) {
        atomicAdd(&hist[dst[e] >> 8], 1);
        atomicAdd(&hist_s[src[e] >> 8], 1);
    }
    __syncthreads();
    for (int t = threadIdx.x; t < NR; t += 1024) {
        hist_g[t * CHUNKS + c]  = hist[t];
        hist_gs[t * CHUNKS + c] = hist_s[t];
    }
}

// scans of region totals + per-chunk cursor tables for both partitions (1 block)
// transposed layout: per-thread strips are contiguous -> int4 streaming
__global__ __launch_bounds__(1024) void region_scan_kernel(const int* __restrict__ hist_g,
                                                           const int* __restrict__ hist_gs,
                                                           int* __restrict__ rstart,
                                                           int* __restrict__ cursor,
                                                           int* __restrict__ sstart,
                                                           int* __restrict__ scursor,
                                                           int NR, int E) {
    __shared__ int wsum[16];
    int tid = threadIdx.x, lane = tid & 63, w = tid >> 6;
    // ---- scan 1: dst totals ----
    int total = 0;
    if (tid < NR) {
        const int4* hp = (const int4*)(hist_g + (size_t)tid * CHUNKS);
        #pragma unroll 8
        for (int c4 = 0; c4 < CHUNKS / 4; c4++) {
            int4 h = hp[c4];
            total += h.x + h.y + h.z + h.w;
        }
    }
    int x = total;
    #pragma unroll
    for (int d = 1; d < 64; d <<= 1) {
        int t = __shfl_up(x, d, 64);
        if (lane >= d) x += t;
    }
    if (lane == 63) wsum[w] = x;
    __syncthreads();
    if (w == 0) {
        int s = (lane < 16) ? wsum[lane] : 0;
        #pragma unroll
        for (int d = 1; d < 16; d <<= 1) {
            int t = __shfl_up(s, d, 64);
            if (lane >= d) s += t;
        }
        if (lane < 16) wsum[lane] = s;
    }
    __syncthreads();
    int off = (w == 0) ? 0 : wsum[w - 1];
    if (tid < NR) {
        int start = x + off - total;
        rstart[tid] = start;
        int run = start;
        const int4* hp = (const int4*)(hist_g + (size_t)tid * CHUNKS);
        int4* cp = (int4*)(cursor + (size_t)tid * CHUNKS);
        #pragma unroll 8
        for (int c4 = 0; c4 < CHUNKS / 4; c4++) {
            int4 h = hp[c4];
            int4 o;
            o.x = run; run += h.x;
            o.y = run; run += h.y;
            o.z = run; run += h.z;
            o.w = run; run += h.w;
            cp[c4] = o;
        }
    }
    if (tid == 0) rstart[NR] = E;
    __syncthreads();
    // ---- scan 2: src totals ----
    total = 0;
    if (tid < NR) {
        const int4* hp = (const int4*)(hist_gs + (size_t)tid * CHUNKS);
        #pragma unroll 8
        for (int c4 = 0; c4 < CHUNKS / 4; c4++) {
            int4 h = hp[c4];
            total += h.x + h.y + h.z + h.w;
        }
    }
    x = total;
    #pragma unroll
    for (int d = 1; d < 64; d <<= 1) {
        int t = __shfl_up(x, d, 64);
        if (lane >= d) x += t;
    }
    if (lane == 63) wsum[w] = x;
    __syncthreads();
    if (w == 0) {
        int s = (lane < 16) ? wsum[lane] : 0;
        #pragma unroll
        for (int d = 1; d < 16; d <<= 1) {
            int t = __shfl_up(s, d, 64);
            if (lane >= d) s += t;
        }
        if (lane < 16) wsum[lane] = s;
    }
    __syncthreads();
    off = (w == 0) ? 0 : wsum[w - 1];
    if (tid < NR) {
        int start = x + off - total;
        sstart[tid] = start;
        int run = start;
        const int4* hp = (const int4*)(hist_gs + (size_t)tid * CHUNKS);
        int4* cp = (int4*)(scursor + (size_t)tid * CHUNKS);
        #pragma unroll 8
        for (int c4 = 0; c4 < CHUNKS / 4; c4++) {
            int4 h = hp[c4];
            int4 o;
            o.x = run; run += h.x;
            o.y = run; run += h.y;
            o.z = run; run += h.z;
            o.w = run; run += h.w;
            cp[c4] = o;
        }
    }
    if (tid == 0) sstart[NR] = E;
}

// dual scatter via LDS cursors: epack=((dst&255)<<17|src) by dst-region,
// spack=(src&255) bytes by src-region. NO per-edge global atomics.
__global__ __launch_bounds__(1024) void partition_kernel(const int* __restrict__ src,
                                                         const int* __restrict__ dst,
                                                         const int* __restrict__ cursor,
                                                         const int* __restrict__ scursor,
                                                         int* __restrict__ epack,
                                                         unsigned char* __restrict__ spack,
                                                         int E, int NR, int CS) {
    __shared__ int cur[NRMAX];
    __shared__ int scur[NRMAX];
    int c = blockIdx.x;
    for (int t = threadIdx.x; t < NR; t += 1024) {
        cur[t]  = cursor[(size_t)t * CHUNKS + c];
        scur[t] = scursor[(size_t)t * CHUNKS + c];
    }
    __syncthreads();
    int e0 = c * CS, e1 = min(e0 + CS, E);
    int nv = (e1 - e0) & ~3;
    for (int e = e0 + threadIdx.x * 4; e < e0 + nv; e += 4096) {
        int4 d = *(const int4*)(dst + e);
        int4 s = *(const int4*)(src + e);
        int p0 = atomicAdd(&cur[d.x >> 8], 1);
        int p1 = atomicAdd(&cur[d.y >> 8], 1);
        int p2 = atomicAdd(&cur[d.z >> 8], 1);
        int p3 = atomicAdd(&cur[d.w >> 8], 1);
        epack[p0] = ((d.x & 255) << 17) | s.x;
        epack[p1] = ((d.y & 255) << 17) | s.y;
        epack[p2] = ((d.z & 255) << 17) | s.z;
        epack[p3] = ((d.w & 255) << 17) | s.w;
        int q0 = atomicAdd(&scur[s.x >> 8], 1);
        int q1 = atomicAdd(&scur[s.y >> 8], 1);
        int q2 = atomicAdd(&scur[s.z >> 8], 1);
        int q3 = atomicAdd(&scur[s.w >> 8], 1);
        spack[q0] = (unsigned char)(s.x & 255);
        spack[q1] = (unsigned char)(s.y & 255);
        spack[q2] = (unsigned char)(s.z & 255);
        spack[q3] = (unsigned char)(s.w & 255);
    }
    for (int e = e0 + nv + threadIdx.x; e < e1; e += 1024) {
        int d = dst[e], s = src[e];
        int pos = atomicAdd(&cur[d >> 8], 1);
        epack[pos] = ((d & 255) << 17) | s;
        int qos = atomicAdd(&scur[s >> 8], 1);
        spack[qos] = (unsigned char)(s & 255);
    }
}

// ---------------- pass 2a: per-region LDS counting sort -> exact CSR ----------------
__global__ __launch_bounds__(1024) void region_sort_kernel(const int* __restrict__ epack,
                                                           const int* __restrict__ rstart,
                                                           int* __restrict__ csrc,
                                                           int* __restrict__ row_start,
                                                           float* __restrict__ r_in,
                                                           int N, int NR, int E) {
    __shared__ int cnt[RN];
    __shared__ int cur[RN];
    __shared__ int wsum[16];
    const int r = blockIdx.x, tid = threadIdx.x;
    const int lane = tid & 63, w = tid >> 6;
    const int s0 = rstart[r], s1 = rstart[r + 1];
    if (tid < RN) cnt[tid] = 0;
    __syncthreads();
    for (int e = s0 + tid; e < s1; e += 1024)
        atomicAdd(&cnt[epack[e] >> 17], 1);
    __syncthreads();
    int cv = (tid < RN) ? cnt[tid] : 0;
    int x = cv;
    #pragma unroll
    for (int d = 1; d < 64; d <<= 1) {
        int t = __shfl_up(x, d, 64);
        if (lane >= d) x += t;
    }
    if (lane == 63 && w < 4) wsum[w] = x;
    __syncthreads();
    if (tid < RN) {
        int woff = 0;
        for (int i = 0; i < w; i++) woff += wsum[i];
        int start = s0 + x - cv + woff;
        cur[tid] = start;
        int node = r * RN + tid;
        if (node < N) {
            row_start[node] = start;
            r_in[node] = rsqrtf((float)max(cv, 1));
        }
    }
    if (r == NR - 1 && tid == 0) row_start[N] = E;
    __syncthreads();
    for (int e = s0 + tid; e < s1; e += 1024) {
        int pk = epack[e];
        int pos = atomicAdd(&cur[pk >> 17], 1);
        csrc[pos] = pk & 0x1FFFF;
    }
}

// ---------------- pass 2b: per-region byte histogram -> r_out ----------------
__global__ __launch_bounds__(256) void rout2_kernel(const unsigned char* __restrict__ spack,
                                                    const int* __restrict__ sstart,
                                                    float* __restrict__ r_out, int N) {
    __shared__ int cnt[RN];
    const int r = blockIdx.x, tid = threadIdx.x;
    const int s0 = sstart[r], s1 = sstart[r + 1];
    cnt[tid] = 0;
    __syncthreads();
    for (int e = s0 + tid; e < s1; e += 256)
        atomicAdd(&cnt[spack[e]], 1);
    __syncthreads();
    int node = r * RN + tid;
    if (node < N) r_out[node] = rsqrtf((float)max(cnt[tid], 1));
}

// ---------------- chunked aggregation v3: peeled, VALU-lean ----------------
// blockIdx.y = feature chunk; table slice [N][32] fp16 (64B rows) is L2-resident.
// One wave per node; lane = (g=lane>>3, o=lane&7): g = edge slot in a group of 8,
// o = 8-byte sub-row. deg is wave-uniform -> full groups run with ZERO masking
// (the round-3 version paid min+cmp+2 cndmask on every gather and padded every
// node to 64 edges -> VALU-bound at 66% busy). One masked tail group per node.
__device__ __forceinline__ void acc4(uint2 d, float& a0, float& a1, float& a2, float& a3) {
    union { uint2 q; __half2 h[2]; } t; t.q = d;
    float2 f0 = __half22float2(t.h[0]);
    float2 f1 = __half22float2(t.h[1]);
    a0 += f0.x; a1 += f0.y; a2 += f1.x; a3 += f1.y;
}

__global__ __launch_bounds__(256) void agg32h_kernel(const __half* __restrict__ Tbase,
                                                     const float* __restrict__ r_in,
                                                     const int* __restrict__ rs,
                                                     const int* __restrict__ csrc,
                                                     __half* __restrict__ Zbase, int N) {
    const int lane = threadIdx.x & 63, wv = threadIdx.x >> 6;
    const int g = lane >> 3, o = lane & 7;
    const int c = blockIdx.y;
    const char* T = (const char*)Tbase + (size_t)c * N * (FC * 2);
    __half* Z = Zbase + (size_t)c * N * FC;
    int v = blockIdx.x * 4 + wv;
    if (v >= N) return;
    int s0 = __builtin_amdgcn_readfirstlane(rs[v]);
    int s1 = __builtin_amdgcn_readfirstlane(rs[v + 1]);
    const int deg = s1 - s0;
    const int nf = deg >> 3, rem = deg & 7;
    const int* cp = csrc + s0;
    float a0 = 0.f, a1 = 0.f, a2 = 0.f, a3 = 0.f;
    int u = 0;
    for (; u + 4 <= nf; u += 4) {
        int i0 = __builtin_nontemporal_load(cp + 8 * (u + 0) + g);
        int i1 = __builtin_nontemporal_load(cp + 8 * (u + 1) + g);
        int i2 = __builtin_nontemporal_load(cp + 8 * (u + 2) + g);
        int i3 = __builtin_nontemporal_load(cp + 8 * (u + 3) + g);
        uint2 d0 = *(const uint2*)(T + (((size_t)(unsigned)i0) << 6) + (o << 3));
        uint2 d1 = *(const uint2*)(T + (((size_t)(unsigned)i1) << 6) + (o << 3));
        uint2 d2 = *(const uint2*)(T + (((size_t)(unsigned)i2) << 6) + (o << 3));
        uint2 d3 = *(const uint2*)(T + (((size_t)(unsigned)i3) << 6) + (o << 3));
        acc4(d0, a0, a1, a2, a3);
        acc4(d1, a0, a1, a2, a3);
        acc4(d2, a0, a1, a2, a3);
        acc4(d3, a0, a1, a2, a3);
    }
    for (; u < nf; u++) {
        int i = __builtin_nontemporal_load(cp + 8 * u + g);
        uint2 d = *(const uint2*)(T + (((size_t)(unsigned)i) << 6) + (o << 3));
        acc4(d, a0, a1, a2, a3);
    }
    if (rem) {  // wave-uniform branch; one masked group
        int i = __builtin_nontemporal_load(cp + 8 * nf + min(g, rem - 1));
        uint2 d = *(const uint2*)(T + (((size_t)(unsigned)i) << 6) + (o << 3));
        unsigned m = (g < rem) ? 0xFFFFFFFFu : 0u;
        d.x &= m; d.y &= m;
        acc4(d, a0, a1, a2, a3);
    }
    // fold the 8 edge-slot groups (lane bits 3..5)
    #pragma unroll
    for (int mskip = 8; mskip <= 32; mskip <<= 1) {
        a0 += __shfl_xor(a0, mskip); a1 += __shfl_xor(a1, mskip);
        a2 += __shfl_xor(a2, mskip); a3 += __shfl_xor(a3, mskip);
    }
    if (g == 0) {
        float ri = r_in[v];
        union { __half2 h[2]; u32x2 v2; } cv;
        cv.h[0] = __floats2half2_rn(a0 * ri, a1 * ri);
        cv.h[1] = __floats2half2_rn(a2 * ri, a3 * ri);
        __builtin_nontemporal_store(cv.v2, (u32x2*)((char*)Z + (((size_t)v) << 6) + (o << 3)));
    }
}

// same gather, fp32 epilogue with bias: out stride OD, blockIdx.y = output chunk
__global__ __launch_bounds__(256) void agg32f_kernel(const __half* __restrict__ Tbase,
                                                     const float* __restrict__ r_in,
                                                     const int* __restrict__ rs,
                                                     const int* __restrict__ csrc,
                                                     const float* __restrict__ bc,
                                                     float* __restrict__ out, int N) {
    const int lane = threadIdx.x & 63, wv = threadIdx.x >> 6;
    const int g = lane >> 3, o = lane & 7;
    const int c = blockIdx.y;
    const char* T = (const char*)Tbase + (size_t)c * N * (FC * 2);
    const float* bcc = bc + c * FC;
    int v = blockIdx.x * 4 + wv;
    if (v >= N) return;
    int s0 = __builtin_amdgcn_readfirstlane(rs[v]);
    int s1 = __builtin_amdgcn_readfirstlane(rs[v + 1]);
    const int deg = s1 - s0;
    const int nf = deg >> 3, rem = deg & 7;
    const int* cp = csrc + s0;
    float a0 = 0.f, a1 = 0.f, a2 = 0.f, a3 = 0.f;
    int u = 0;
    for (; u + 4 <= nf; u += 4) {
        int i0 = __builtin_nontemporal_load(cp + 8 * (u + 0) + g);
        int i1 = __builtin_nontemporal_load(cp + 8 * (u + 1) + g);
        int i2 = __builtin_nontemporal_load(cp + 8 * (u + 2) + g);
        int i3 = __builtin_nontemporal_load(cp + 8 * (u + 3) + g);
        uint2 d0 = *(const uint2*)(T + (((size_t)(unsigned)i0) << 6) + (o << 3));
        uint2 d1 = *(const uint2*)(T + (((size_t)(unsigned)i1) << 6) + (o << 3));
        uint2 d2 = *(const uint2*)(T + (((size_t)(unsigned)i2) << 6) + (o << 3));
        uint2 d3 = *(const uint2*)(T + (((size_t)(unsigned)i3) << 6) + (o << 3));
        acc4(d0, a0, a1, a2, a3);
        acc4(d1, a0, a1, a2, a3);
        acc4(d2, a0, a1, a2, a3);
        acc4(d3, a0, a1, a2, a3);
    }
    for (; u < nf; u++) {
        int i = __builtin_nontemporal_load(cp + 8 * u + g);
        uint2 d = *(const uint2*)(T + (((size_t)(unsigned)i) << 6) + (o << 3));
        acc4(d, a0, a1, a2, a3);
    }
    if (rem) {
        int i = __builtin_nontemporal_load(cp + 8 * nf + min(g, rem - 1));
        uint2 d = *(const uint2*)(T + (((size_t)(unsigned)i) << 6) + (o << 3));
        unsigned m = (g < rem) ? 0xFFFFFFFFu : 0u;
        d.x &= m; d.y &= m;
        acc4(d, a0, a1, a2, a3);
    }
    #pragma unroll
    for (int mskip = 8; mskip <= 32; mskip <<= 1) {
        a0 += __shfl_xor(a0, mskip); a1 += __shfl_xor(a1, mskip);
        a2 += __shfl_xor(a2, mskip); a3 += __shfl_xor(a3, mskip);
    }
    if (g == 0) {
        float ri = r_in[v];
        f32x4 bv = *(const f32x4*)(bcc + 4 * o);
        f32x4 ov;
        ov[0] = a0 * ri + bv[0];
        ov[1] = a1 * ri + bv[1];
        ov[2] = a2 * ri + bv[2];
        ov[3] = a3 * ri + bv[3];
        __builtin_nontemporal_store(ov, (f32x4*)(out + (size_t)v * OD + c * FC + 4 * o));
    }
}

// ---------------- MFMA GEMM 1: y1h = fp16(relu(z1c@W1h + b1) * r_out) ----------------
// A (z1) is chunked [4][N][32]; output y1h row-major [N][128]
__global__ __launch_bounds__(256) void gemm1_mfma_kernel(const __half* __restrict__ Ah,
                                                         const __half* __restrict__ Bh,
                                                         const float* __restrict__ b1,
                                                         const float* __restrict__ rowscale,
                                                         __half* __restrict__ Ch,
                                                         int M, int ntiles) {
    const int w = threadIdx.x >> 6, lane = threadIdx.x & 63;
    const int l15 = lane & 15, quad = lane >> 4;
    const _Float16* B = (const _Float16*)Bh;
    const _Float16* Az = (const _Float16*)Ah;

    f16x8 bfrag[2][4];
    #pragma unroll
    for (int nt = 0; nt < 2; nt++) {
        int col = 32 * w + 16 * nt + l15;
        #pragma unroll
        for (int kk = 0; kk < 4; kk++) {
            int kb = kk * 32 + quad * 8;
            f16x8 bf;
            #pragma unroll
            for (int j = 0; j < 8; j++) bf[j] = B[(size_t)(kb + j) * FD + col];
            bfrag[nt][kk] = bf;
        }
    }

    for (int t = blockIdx.x; t < ntiles; t += gridDim.x) {
        int row0 = t * 16;
        f16x8 afrag[4];
        #pragma unroll
        for (int kk = 0; kk < 4; kk++)
            afrag[kk] = *(const f16x8*)(Az + ((size_t)kk * M + row0 + l15) * FC + quad * 8);
        f32x4 acc0 = {0.f, 0.f, 0.f, 0.f};
        f32x4 acc1 = {0.f, 0.f, 0.f, 0.f};
        #pragma unroll
        for (int kk = 0; kk < 4; kk++) {
            acc0 = __builtin_amdgcn_mfma_f32_16x16x32_f16(afrag[kk], bfrag[0][kk], acc0, 0, 0, 0);
            acc1 = __builtin_amdgcn_mfma_f32_16x16x32_f16(afrag[kk], bfrag[1][kk], acc1, 0, 0, 0);
        }
        int c0 = 32 * w + l15, c1 = c0 + 16;
        float bb0 = b1[c0], bb1 = b1[c1];
        #pragma unroll
        for (int r = 0; r < 4; r++) {
            int row = row0 + quad * 4 + r;
            if (row < M) {
                float rsc = rowscale[row];
                Ch[(size_t)row * FD + c0] = __float2half(fmaxf(acc0[r] + bb0, 0.f) * rsc);
                Ch[(size_t)row * FD + c1] = __float2half(fmaxf(acc1[r] + bb1, 0.f) * rsc);
            }
        }
    }
}

// ---------------- MFMA GEMM 2: tbuf(chunked [2][N][32]) = fp16(y1h @ Wch) (N=64) ----------------
__global__ __launch_bounds__(256) void gemm2_mfma_kernel(const __half* __restrict__ Ah,
                                                         const __half* __restrict__ Bh,
                                                         __half* __restrict__ Ch,
                                                         int M, int ntiles) {
    const int w = threadIdx.x >> 6, lane = threadIdx.x & 63;
    const int l15 = lane & 15, quad = lane >> 4;
    const _Float16* B = (const _Float16*)Bh;

    f16x8 bfrag[4];
    int col = 16 * w + l15;
    const int cc = col >> 5, cw = col & 31;   // output chunk / offset
    #pragma unroll
    for (int kk = 0; kk < 4; kk++) {
        int kb = kk * 32 + quad * 8;
        f16x8 bf;
        #pragma unroll
        for (int j = 0; j < 8; j++) bf[j] = B[(size_t)(kb + j) * OD + col];
        bfrag[kk] = bf;
    }

    for (int t = blockIdx.x; t < ntiles; t += gridDim.x) {
        int row0 = t * 16;
        const _Float16* Arow = (const _Float16*)Ah + (size_t)(row0 + l15) * FD + quad * 8;
        f16x8 afrag[4];
        #pragma unroll
        for (int kk = 0; kk < 4; kk++) afrag[kk] = *(const f16x8*)(Arow + kk * 32);
        f32x4 acc = {0.f, 0.f, 0.f, 0.f};
        #pragma unroll
        for (int kk = 0; kk < 4; kk++)
            acc = __builtin_amdgcn_mfma_f32_16x16x32_f16(afrag[kk], bfrag[kk], acc, 0, 0, 0);
        #pragma unroll
        for (int r = 0; r < 4; r++) {
            int row = row0 + quad * 4 + r;
            if (row < M)
                Ch[((size_t)cc * M + row) * FC + cw] = __float2half(acc[r]);
        }
    }
}

// ---------------- fold: W1h = fp16(W1); Wch = fp16(W2@Wf); bc = b2@Wf + bf ----------------
__global__ void fold_kernel(const float* __restrict__ W2, const float* __restrict__ Wf,
                            const float* __restrict__ b2, const float* __restrict__ bf,
                            const float* __restrict__ W1,
                            __half* __restrict__ W1h, __half* __restrict__ Wch,
                            float* __restrict__ bc) {
    int idx = blockIdx.x * 256 + threadIdx.x;
    if (idx < FD * FD) W1h[idx] = __float2half(W1[idx]);
    if (idx < FD * OD) {
        int i = idx / OD, j = idx % OD;
        float s = 0.f;
        for (int k = 0; k < FD; k++) s += W2[i * FD + k] * Wf[k * OD + j];
        Wch[idx] = __float2half(s);
    }
    if (idx < OD) {
        float s = bf[idx];
        for (int k = 0; k < FD; k++) s += b2[k] * Wf[k * OD + idx];
        bc[idx] = s;
    }
}

// ---------------- launch ----------------
extern "C" void kernel_launch(void* const* d_in, const int* in_sizes, int n_in,
                              void* d_out, int out_size, void* d_ws, size_t ws_size,
                              hipStream_t stream) {
    const float* in_feat = (const float*)d_in[0];
    const int*   src     = (const int*)d_in[1];
    const int*   dst     = (const int*)d_in[2];
    const float* W1      = (const float*)d_in[3];
    const float* b1      = (const float*)d_in[4];
    const float* W2      = (const float*)d_in[5];
    const float* b2      = (const float*)d_in[6];
    const float* Wf      = (const float*)d_in[7];
    const float* bf      = (const float*)d_in[8];
    float* out = (float*)d_out;

    const int N = in_sizes[0] / FD;        // 50000
    const int E = in_sizes[1];             // 1600000
    const int NR = (N + RN - 1) / RN;      // 196 (<= NRMAX)
    const int CS = (((E + CHUNKS - 1) / CHUNKS) + 3) & ~3;  // 4-aligned for int4

    char* ws = (char*)d_ws;
    size_t off = 0;
    auto alloc = [&](size_t bytes) -> void* {
        void* p = ws + off;
        off += (bytes + 255) / 256 * 256;
        return p;
    };
    // spack (1.6 MB) + epack (6.4 MB) adjacent; both dead before gemm2 writes
    // tbuf (N*OD*2 = 6.4 MB) which aliases them.
    unsigned char* spack = (unsigned char*)alloc((size_t)E);
    int*    epack   = (int*)alloc((size_t)E * 4);
    __half* tbuf    = (__half*)spack;              // chunked [2][N][32]
    float*  r_out   = (float*)alloc((size_t)N * 4);
    float*  r_in    = (float*)alloc((size_t)N * 4);
    int*    hist_g  = (int*)alloc((size_t)CHUNKS * NRMAX * 4);
    int*    hist_gs = (int*)alloc((size_t)CHUNKS * NRMAX * 4);
    int*    cursor  = (int*)alloc((size_t)CHUNKS * NRMAX * 4);
    int*    scursor = (int*)alloc((size_t)CHUNKS * NRMAX * 4);
    int*    rstart  = (int*)alloc((size_t)(NR + 1) * 4);
    int*    sstart  = (int*)alloc((size_t)(NR + 1) * 4);
    int*    csrc    = (int*)alloc((size_t)E * 4);
    int*    row_start = (int*)alloc((size_t)(N + 1) * 4);
    __half* z1h     = (__half*)alloc((size_t)N * FD * 2);   // chunked [4][N][32]
    __half* y1h     = (__half*)alloc((size_t)N * FD * 2);   // row-major [N][128]
    __half* Xs      = (__half*)alloc((size_t)N * FD * 2);   // chunked [4][N][32]
    __half* W1h     = (__half*)alloc((size_t)FD * FD * 2);
    __half* Wch     = (__half*)alloc((size_t)FD * OD * 2);
    float*  bc      = (float*)alloc((size_t)OD * 4);
    (void)ws_size; (void)n_in; (void)out_size;

    const int ntiles = (N + 15) / 16;      // 3125
    const int gemmgrid = ntiles < 1024 ? ntiles : 1024;
    const int aggblocks = (N + 3) / 4;

    // exact dst-sort + src-degree count, zero per-edge global atomics:
    // dual region partition (pass 1) then per-region LDS passes (pass 2).
    region_hist_kernel<<<CHUNKS, 1024, 0, stream>>>(src, dst, hist_g, hist_gs, E, NR, CS);
    region_scan_kernel<<<1, 1024, 0, stream>>>(hist_g, hist_gs, rstart, cursor, sstart, scursor, NR, E);
    partition_kernel<<<CHUNKS, 1024, 0, stream>>>(src, dst, cursor, scursor, epack, spack, E, NR, CS);
    region_sort_kernel<<<NR, 1024, 0, stream>>>(epack, rstart, csrc, row_start, r_in, N, NR, E);
    rout2_kernel<<<NR, 256, 0, stream>>>(spack, sstart, r_out, N);

    // fold weights (fp16) + combined final bias
    fold_kernel<<<(FD * FD + 255) / 256, 256, 0, stream>>>(W2, Wf, b2, bf, W1, W1h, Wch, bc);

    // layer 1: Xs = half(r_out*x) chunked; z1 = half(r_in*Agg(Xs)) chunked.
    // one fused dispatch, gridDim.y = 4 chunks (x-major order => sequential phases),
    // nt streams keep each 3.2MB table slice L2-resident.
    prescale_kernel<<<(N * 32 + 255) / 256, 256, 0, stream>>>(in_feat, r_out, Xs, N * 32, N);
    agg32h_kernel<<<dim3(aggblocks, 4), 256, 0, stream>>>(Xs, r_in, row_start, csrc, z1h, N);

    // MFMA GEMMs: y1h = relu(z1c@W1h+b1)*r_out ; tbuf(chunked) = y1h@Wch
    gemm1_mfma_kernel<<<gemmgrid, 256, 0, stream>>>(z1h, W1h, b1, r_out, y1h, N, ntiles);
    gemm2_mfma_kernel<<<gemmgrid, 256, 0, stream>>>(y1h, Wch, tbuf, N, ntiles);

    // final: out = r_in*Agg(tbuf) + bc, gridDim.y = 2 chunks
    agg32f_kernel<<<dim3(aggblocks, 2), 256, 0, stream>>>(tbuf, r_in, row_start, csrc, bc, out, N);
}

// Round 5
// 287.024 us; speedup vs baseline: 1.3076x; 1.3076x over previous
//
#include <hip/hip_runtime.h>
#include <hip/hip_fp16.h>

#define FD 128    // hidden feature dim
#define OD 64     // output dim
#define RN 256    // nodes per region (id >> 8)
#define CHUNKS 256
#define NRMAX 1024

typedef _Float16 f16x8 __attribute__((ext_vector_type(8)));
typedef float    f32x4 __attribute__((ext_vector_type(4)));
typedef float    f32x2 __attribute__((ext_vector_type(2)));

// ---------------- misc ----------------

// Xs(half, row-major [N][128]) = r_out (row) * X ; one float4 -> 4 halves per thread
__global__ void prescale_kernel(const float* __restrict__ X, const float* __restrict__ r_out,
                                __half* __restrict__ Xs, int n4) {
    int i = blockIdx.x * 256 + threadIdx.x;
    if (i >= n4) return;
    int v = i >> 5;                    // 32 float4 per 128-float row
    float r = r_out[v];
    float4 t = ((const float4*)X)[i];
    ((__half2*)Xs)[2 * i]     = __floats2half2_rn(t.x * r, t.y * r);
    ((__half2*)Xs)[2 * i + 1] = __floats2half2_rn(t.z * r, t.w * r);
}

// ---------------- pass 1: dual histograms by region (dst>>8 and src>>8) ----------------
// hist layout TRANSPOSED: hist_g[region * CHUNKS + chunk] so the scan kernel streams.

__global__ __launch_bounds__(1024) void region_hist_kernel(const int* __restrict__ src,
                                                           const int* __restrict__ dst,
                                                           int* __restrict__ hist_g,
                                                           int* __restrict__ hist_gs,
                                                           int E, int NR, int CS) {
    __shared__ int hist[NRMAX];
    __shared__ int hist_s[NRMAX];
    int c = blockIdx.x;
    for (int t = threadIdx.x; t < NR; t += 1024) { hist[t] = 0; hist_s[t] = 0; }
    __syncthreads();
    int e0 = c * CS, e1 = min(e0 + CS, E);
    int nv = (e1 - e0) & ~3;
    for (int e = e0 + threadIdx.x * 4; e < e0 + nv; e += 4096) {
        int4 d = *(const int4*)(dst + e);
        int4 s = *(const int4*)(src + e);
        atomicAdd(&hist[d.x >> 8], 1);
        atomicAdd(&hist[d.y >> 8], 1);
        atomicAdd(&hist[d.z >> 8], 1);
        atomicAdd(&hist[d.w >> 8], 1);
        atomicAdd(&hist_s[s.x >> 8], 1);
        atomicAdd(&hist_s[s.y >> 8], 1);
        atomicAdd(&hist_s[s.z >> 8], 1);
        atomicAdd(&hist_s[s.w >> 8], 1);
    }
    for (int e = e0 + nv + threadIdx.x; e < e1; e += 1024) {
        atomicAdd(&hist[dst[e] >> 8], 1);
        atomicAdd(&hist_s[src[e] >> 8], 1);
    }
    __syncthreads();
    for (int t = threadIdx.x; t < NR; t += 1024) {
        hist_g[t * CHUNKS + c]  = hist[t];
        hist_gs[t * CHUNKS + c] = hist_s[t];
    }
}

// scans of region totals + per-chunk cursor tables for both partitions (1 block)
// transposed layout: per-thread strips are contiguous -> int4 streaming
__global__ __launch_bounds__(1024) void region_scan_kernel(const int* __restrict__ hist_g,
                                                           const int* __restrict__ hist_gs,
                                                           int* __restrict__ rstart,
                                                           int* __restrict__ cursor,
                                                           int* __restrict__ sstart,
                                                           int* __restrict__ scursor,
                                                           int NR, int E) {
    __shared__ int wsum[16];
    int tid = threadIdx.x, lane = tid & 63, w = tid >> 6;
    // ---- scan 1: dst totals ----
    int total = 0;
    if (tid < NR) {
        const int4* hp = (const int4*)(hist_g + (size_t)tid * CHUNKS);
        #pragma unroll 8
        for (int c4 = 0; c4 < CHUNKS / 4; c4++) {
            int4 h = hp[c4];
            total += h.x + h.y + h.z + h.w;
        }
    }
    int x = total;
    #pragma unroll
    for (int d = 1; d < 64; d <<= 1) {
        int t = __shfl_up(x, d, 64);
        if (lane >= d) x += t;
    }
    if (lane == 63) wsum[w] = x;
    __syncthreads();
    if (w == 0) {
        int s = (lane < 16) ? wsum[lane] : 0;
        #pragma unroll
        for (int d = 1; d < 16; d <<= 1) {
            int t = __shfl_up(s, d, 64);
            if (lane >= d) s += t;
        }
        if (lane < 16) wsum[lane] = s;
    }
    __syncthreads();
    int off = (w == 0) ? 0 : wsum[w - 1];
    if (tid < NR) {
        int start = x + off - total;
        rstart[tid] = start;
        int run = start;
        const int4* hp = (const int4*)(hist_g + (size_t)tid * CHUNKS);
        int4* cp = (int4*)(cursor + (size_t)tid * CHUNKS);
        #pragma unroll 8
        for (int c4 = 0; c4 < CHUNKS / 4; c4++) {
            int4 h = hp[c4];
            int4 o;
            o.x = run; run += h.x;
            o.y = run; run += h.y;
            o.z = run; run += h.z;
            o.w = run; run += h.w;
            cp[c4] = o;
        }
    }
    if (tid == 0) rstart[NR] = E;
    __syncthreads();
    // ---- scan 2: src totals ----
    total = 0;
    if (tid < NR) {
        const int4* hp = (const int4*)(hist_gs + (size_t)tid * CHUNKS);
        #pragma unroll 8
        for (int c4 = 0; c4 < CHUNKS / 4; c4++) {
            int4 h = hp[c4];
            total += h.x + h.y + h.z + h.w;
        }
    }
    x = total;
    #pragma unroll
    for (int d = 1; d < 64; d <<= 1) {
        int t = __shfl_up(x, d, 64);
        if (lane >= d) x += t;
    }
    if (lane == 63) wsum[w] = x;
    __syncthreads();
    if (w == 0) {
        int s = (lane < 16) ? wsum[lane] : 0;
        #pragma unroll
        for (int d = 1; d < 16; d <<= 1) {
            int t = __shfl_up(s, d, 64);
            if (lane >= d) s += t;
        }
        if (lane < 16) wsum[lane] = s;
    }
    __syncthreads();
    off = (w == 0) ? 0 : wsum[w - 1];
    if (tid < NR) {
        int start = x + off - total;
        sstart[tid] = start;
        int run = start;
        const int4* hp = (const int4*)(hist_gs + (size_t)tid * CHUNKS);
        int4* cp = (int4*)(scursor + (size_t)tid * CHUNKS);
        #pragma unroll 8
        for (int c4 = 0; c4 < CHUNKS / 4; c4++) {
            int4 h = hp[c4];
            int4 o;
            o.x = run; run += h.x;
            o.y = run; run += h.y;
            o.z = run; run += h.z;
            o.w = run; run += h.w;
            cp[c4] = o;
        }
    }
    if (tid == 0) sstart[NR] = E;
}

// dual scatter via LDS cursors: epack=((dst&255)<<17|src) by dst-region,
// spack=(src&255) bytes by src-region. NO per-edge global atomics.
__global__ __launch_bounds__(1024) void partition_kernel(const int* __restrict__ src,
                                                         const int* __restrict__ dst,
                                                         const int* __restrict__ cursor,
                                                         const int* __restrict__ scursor,
                                                         int* __restrict__ epack,
                                                         unsigned char* __restrict__ spack,
                                                         int E, int NR, int CS) {
    __shared__ int cur[NRMAX];
    __shared__ int scur[NRMAX];
    int c = blockIdx.x;
    for (int t = threadIdx.x; t < NR; t += 1024) {
        cur[t]  = cursor[(size_t)t * CHUNKS + c];
        scur[t] = scursor[(size_t)t * CHUNKS + c];
    }
    __syncthreads();
    int e0 = c * CS, e1 = min(e0 + CS, E);
    int nv = (e1 - e0) & ~3;
    for (int e = e0 + threadIdx.x * 4; e < e0 + nv; e += 4096) {
        int4 d = *(const int4*)(dst + e);
        int4 s = *(const int4*)(src + e);
        int p0 = atomicAdd(&cur[d.x >> 8], 1);
        int p1 = atomicAdd(&cur[d.y >> 8], 1);
        int p2 = atomicAdd(&cur[d.z >> 8], 1);
        int p3 = atomicAdd(&cur[d.w >> 8], 1);
        epack[p0] = ((d.x & 255) << 17) | s.x;
        epack[p1] = ((d.y & 255) << 17) | s.y;
        epack[p2] = ((d.z & 255) << 17) | s.z;
        epack[p3] = ((d.w & 255) << 17) | s.w;
        int q0 = atomicAdd(&scur[s.x >> 8], 1);
        int q1 = atomicAdd(&scur[s.y >> 8], 1);
        int q2 = atomicAdd(&scur[s.z >> 8], 1);
        int q3 = atomicAdd(&scur[s.w >> 8], 1);
        spack[q0] = (unsigned char)(s.x & 255);
        spack[q1] = (unsigned char)(s.y & 255);
        spack[q2] = (unsigned char)(s.z & 255);
        spack[q3] = (unsigned char)(s.w & 255);
    }
    for (int e = e0 + nv + threadIdx.x; e < e1; e += 1024) {
        int d = dst[e], s = src[e];
        int pos = atomicAdd(&cur[d >> 8], 1);
        epack[pos] = ((d & 255) << 17) | s;
        int qos = atomicAdd(&scur[s >> 8], 1);
        spack[qos] = (unsigned char)(s & 255);
    }
}

// ---------------- pass 2a: per-region LDS counting sort -> exact CSR ----------------
__global__ __launch_bounds__(1024) void region_sort_kernel(const int* __restrict__ epack,
                                                           const int* __restrict__ rstart,
                                                           int* __restrict__ csrc,
                                                           int* __restrict__ row_start,
                                                           float* __restrict__ r_in,
                                                           int N, int NR, int E) {
    __shared__ int cnt[RN];
    __shared__ int cur[RN];
    __shared__ int wsum[16];
    const int r = blockIdx.x, tid = threadIdx.x;
    const int lane = tid & 63, w = tid >> 6;
    const int s0 = rstart[r], s1 = rstart[r + 1];
    if (tid < RN) cnt[tid] = 0;
    __syncthreads();
    for (int e = s0 + tid; e < s1; e += 1024)
        atomicAdd(&cnt[epack[e] >> 17], 1);
    __syncthreads();
    int cv = (tid < RN) ? cnt[tid] : 0;
    int x = cv;
    #pragma unroll
    for (int d = 1; d < 64; d <<= 1) {
        int t = __shfl_up(x, d, 64);
        if (lane >= d) x += t;
    }
    if (lane == 63 && w < 4) wsum[w] = x;
    __syncthreads();
    if (tid < RN) {
        int woff = 0;
        for (int i = 0; i < w; i++) woff += wsum[i];
        int start = s0 + x - cv + woff;
        cur[tid] = start;
        int node = r * RN + tid;
        if (node < N) {
            row_start[node] = start;
            r_in[node] = rsqrtf((float)max(cv, 1));
        }
    }
    if (r == NR - 1 && tid == 0) row_start[N] = E;
    __syncthreads();
    for (int e = s0 + tid; e < s1; e += 1024) {
        int pk = epack[e];
        int pos = atomicAdd(&cur[pk >> 17], 1);
        csrc[pos] = pk & 0x1FFFF;
    }
}

// ---------------- pass 2b: per-region byte histogram -> r_out ----------------
__global__ __launch_bounds__(256) void rout2_kernel(const unsigned char* __restrict__ spack,
                                                    const int* __restrict__ sstart,
                                                    float* __restrict__ r_out, int N) {
    __shared__ int cnt[RN];
    const int r = blockIdx.x, tid = threadIdx.x;
    const int s0 = sstart[r], s1 = sstart[r + 1];
    cnt[tid] = 0;
    __syncthreads();
    for (int e = s0 + tid; e < s1; e += 256)
        atomicAdd(&cnt[spack[e]], 1);
    __syncthreads();
    int node = r * RN + tid;
    if (node < N) r_out[node] = rsqrtf((float)max(cnt[tid], 1));
}

// ---------------- aggregation: one wave per node, 256B rows, pipelined ----------------
// Round-0 structure (best measured) with two fixes:
//  - idx prefetch: batch k+1's csrc loads issue before batch k's accumulate,
//    removing the idx round-trip from steady state.
//  - tail: ONE masked 16-batch (clamped idx, uniform-rem cndmask) replaces the
//    4-batch + scalar loops (~3-4 dependent round trips -> 1).
// csrc reads + Z writes non-temporal so the 12.8MB Xs table keeps more L2.
__global__ __launch_bounds__(256) void agg128_kernel(const __half* __restrict__ Xs,
                                                     const float* __restrict__ r_in,
                                                     const int* __restrict__ rs,
                                                     const int* __restrict__ csrc,
                                                     __half* __restrict__ Z, int N) {
    const int lane = threadIdx.x & 63, wv = threadIdx.x >> 6;
    int v = blockIdx.x * 4 + wv;
    if (v >= N) return;
    int s0 = __builtin_amdgcn_readfirstlane(rs[v]);
    int s1 = __builtin_amdgcn_readfirstlane(rs[v + 1]);
    const int deg = s1 - s0;
    float ax = 0.f, ay = 0.f;
    const int nb = deg >> 4;
    int e = s0;
    if (nb) {
        int ia[16];
        #pragma unroll
        for (int u = 0; u < 16; u++) ia[u] = __builtin_nontemporal_load(csrc + e + u);
        for (int b = 1; b < nb; b++) {
            __half2 t[16];
            #pragma unroll
            for (int u = 0; u < 16; u++)
                t[u] = ((const __half2*)(Xs + (size_t)ia[u] * FD))[lane];
            int eb = e + (b << 4);
            #pragma unroll
            for (int u = 0; u < 16; u++) ia[u] = __builtin_nontemporal_load(csrc + eb + u);
            #pragma unroll
            for (int u = 0; u < 16; u++) {
                float2 f = __half22float2(t[u]);
                ax += f.x; ay += f.y;
            }
        }
        __half2 t[16];
        #pragma unroll
        for (int u = 0; u < 16; u++)
            t[u] = ((const __half2*)(Xs + (size_t)ia[u] * FD))[lane];
        #pragma unroll
        for (int u = 0; u < 16; u++) {
            float2 f = __half22float2(t[u]);
            ax += f.x; ay += f.y;
        }
        e += nb << 4;
    }
    const int rem = s1 - e;          // 0..15, wave-uniform
    if (rem) {
        const int last = s1 - 1;
        int ia[16];
        #pragma unroll
        for (int u = 0; u < 16; u++)
            ia[u] = __builtin_nontemporal_load(csrc + min(e + u, last));
        #pragma unroll
        for (int u = 0; u < 16; u++) {
            unsigned raw = ((const unsigned*)(Xs + (size_t)ia[u] * FD))[lane];
            raw = (u < rem) ? raw : 0u;
            union { unsigned q; __half2 h; } tt; tt.q = raw;
            float2 f = __half22float2(tt.h);
            ax += f.x; ay += f.y;
        }
    }
    float ri = r_in[v];
    union { __half2 h; unsigned q; } o;
    o.h = __floats2half2_rn(ax * ri, ay * ri);
    __builtin_nontemporal_store(o.q, (unsigned*)(Z + (size_t)v * FD) + lane);
}

// 2 nodes per wave, 32 lanes x half2 each (4B/lane loads, 128B/row), same pipelining
__global__ __launch_bounds__(256) void agg64_kernel(const __half* __restrict__ T,
                                                    const float* __restrict__ r_in,
                                                    const int* __restrict__ rs,
                                                    const int* __restrict__ csrc,
                                                    const float* __restrict__ bc,
                                                    float* __restrict__ out, int N) {
    const int tid = threadIdx.x;
    const int lane = tid & 63, wv = tid >> 6;
    const int hf = lane >> 5, l32 = lane & 31;
    int v = blockIdx.x * 8 + wv * 2 + hf;
    if (v >= N) return;
    int s0 = rs[v], s1 = rs[v + 1];          // half-wave uniform
    const int deg = s1 - s0;
    float ax = 0.f, ay = 0.f;
    const int nb = deg >> 3;
    int e = s0;
    if (nb) {
        int ia[8];
        #pragma unroll
        for (int u = 0; u < 8; u++) ia[u] = __builtin_nontemporal_load(csrc + e + u);
        for (int b = 1; b < nb; b++) {
            __half2 t[8];
            #pragma unroll
            for (int u = 0; u < 8; u++)
                t[u] = ((const __half2*)(T + (size_t)ia[u] * OD))[l32];
            int eb = e + (b << 3);
            #pragma unroll
            for (int u = 0; u < 8; u++) ia[u] = __builtin_nontemporal_load(csrc + eb + u);
            #pragma unroll
            for (int u = 0; u < 8; u++) {
                float2 f = __half22float2(t[u]);
                ax += f.x; ay += f.y;
            }
        }
        __half2 t[8];
        #pragma unroll
        for (int u = 0; u < 8; u++)
            t[u] = ((const __half2*)(T + (size_t)ia[u] * OD))[l32];
        #pragma unroll
        for (int u = 0; u < 8; u++) {
            float2 f = __half22float2(t[u]);
            ax += f.x; ay += f.y;
        }
        e += nb << 3;
    }
    const int rem = s1 - e;                  // 0..7 (per half-wave)
    if (rem) {
        const int last = s1 - 1;
        int ia[8];
        #pragma unroll
        for (int u = 0; u < 8; u++)
            ia[u] = __builtin_nontemporal_load(csrc + min(e + u, last));
        #pragma unroll
        for (int u = 0; u < 8; u++) {
            unsigned raw = ((const unsigned*)(T + (size_t)ia[u] * OD))[l32];
            raw = (u < rem) ? raw : 0u;
            union { unsigned q; __half2 h; } tt; tt.q = raw;
            float2 f = __half22float2(tt.h);
            ax += f.x; ay += f.y;
        }
    }
    float ri = r_in[v];
    f32x2 o;
    o.x = ax * ri + bc[l32 * 2];
    o.y = ay * ri + bc[l32 * 2 + 1];
    __builtin_nontemporal_store(o, (f32x2*)(out + (size_t)v * OD) + l32);
}

// ---------------- MFMA GEMM 1: y1h = fp16(relu(z1h@W1h + b1) * r_out) ----------------
__global__ __launch_bounds__(256) void gemm1_mfma_kernel(const __half* __restrict__ Ah,
                                                         const __half* __restrict__ Bh,
                                                         const float* __restrict__ b1,
                                                         const float* __restrict__ rowscale,
                                                         __half* __restrict__ Ch,
                                                         int M, int ntiles) {
    const int w = threadIdx.x >> 6, lane = threadIdx.x & 63;
    const int l15 = lane & 15, quad = lane >> 4;
    const _Float16* B = (const _Float16*)Bh;

    f16x8 bfrag[2][4];
    #pragma unroll
    for (int nt = 0; nt < 2; nt++) {
        int col = 32 * w + 16 * nt + l15;
        #pragma unroll
        for (int kk = 0; kk < 4; kk++) {
            int kb = kk * 32 + quad * 8;
            f16x8 bf;
            #pragma unroll
            for (int j = 0; j < 8; j++) bf[j] = B[(size_t)(kb + j) * FD + col];
            bfrag[nt][kk] = bf;
        }
    }

    for (int t = blockIdx.x; t < ntiles; t += gridDim.x) {
        int row0 = t * 16;
        const _Float16* Arow = (const _Float16*)Ah + (size_t)(row0 + l15) * FD + quad * 8;
        f16x8 afrag[4];
        #pragma unroll
        for (int kk = 0; kk < 4; kk++) afrag[kk] = *(const f16x8*)(Arow + kk * 32);
        f32x4 acc0 = {0.f, 0.f, 0.f, 0.f};
        f32x4 acc1 = {0.f, 0.f, 0.f, 0.f};
        #pragma unroll
        for (int kk = 0; kk < 4; kk++) {
            acc0 = __builtin_amdgcn_mfma_f32_16x16x32_f16(afrag[kk], bfrag[0][kk], acc0, 0, 0, 0);
            acc1 = __builtin_amdgcn_mfma_f32_16x16x32_f16(afrag[kk], bfrag[1][kk], acc1, 0, 0, 0);
        }
        int c0 = 32 * w + l15, c1 = c0 + 16;
        float bb0 = b1[c0], bb1 = b1[c1];
        #pragma unroll
        for (int r = 0; r < 4; r++) {
            int row = row0 + quad * 4 + r;
            if (row < M) {
                float rsc = rowscale[row];
                Ch[(size_t)row * FD + c0] = __float2half(fmaxf(acc0[r] + bb0, 0.f) * rsc);
                Ch[(size_t)row * FD + c1] = __float2half(fmaxf(acc1[r] + bb1, 0.f) * rsc);
            }
        }
    }
}

// ---------------- MFMA GEMM 2: tbuf = fp16(y1h @ Wch) (N=64) ----------------
__global__ __launch_bounds__(256) void gemm2_mfma_kernel(const __half* __restrict__ Ah,
                                                         const __half* __restrict__ Bh,
                                                         __half* __restrict__ Ch,
                                                         int M, int ntiles) {
    const int w = threadIdx.x >> 6, lane = threadIdx.x & 63;
    const int l15 = lane & 15, quad = lane >> 4;
    const _Float16* B = (const _Float16*)Bh;

    f16x8 bfrag[4];
    int col = 16 * w + l15;
    #pragma unroll
    for (int kk = 0; kk < 4; kk++) {
        int kb = kk * 32 + quad * 8;
        f16x8 bf;
        #pragma unroll
        for (int j = 0; j < 8; j++) bf[j] = B[(size_t)(kb + j) * OD + col];
        bfrag[kk] = bf;
    }

    for (int t = blockIdx.x; t < ntiles; t += gridDim.x) {
        int row0 = t * 16;
        const _Float16* Arow = (const _Float16*)Ah + (size_t)(row0 + l15) * FD + quad * 8;
        f16x8 afrag[4];
        #pragma unroll
        for (int kk = 0; kk < 4; kk++) afrag[kk] = *(const f16x8*)(Arow + kk * 32);
        f32x4 acc = {0.f, 0.f, 0.f, 0.f};
        #pragma unroll
        for (int kk = 0; kk < 4; kk++)
            acc = __builtin_amdgcn_mfma_f32_16x16x32_f16(afrag[kk], bfrag[kk], acc, 0, 0, 0);
        #pragma unroll
        for (int r = 0; r < 4; r++) {
            int row = row0 + quad * 4 + r;
            if (row < M)
                Ch[(size_t)row * OD + col] = __float2half(acc[r]);
        }
    }
}

// ---------------- fold: W1h = fp16(W1); Wch = fp16(W2@Wf); bc = b2@Wf + bf ----------------
__global__ void fold_kernel(const float* __restrict__ W2, const float* __restrict__ Wf,
                            const float* __restrict__ b2, const float* __restrict__ bf,
                            const float* __restrict__ W1,
                            __half* __restrict__ W1h, __half* __restrict__ Wch,
                            float* __restrict__ bc) {
    int idx = blockIdx.x * 256 + threadIdx.x;
    if (idx < FD * FD) W1h[idx] = __float2half(W1[idx]);
    if (idx < FD * OD) {
        int i = idx / OD, j = idx % OD;
        float s = 0.f;
        for (int k = 0; k < FD; k++) s += W2[i * FD + k] * Wf[k * OD + j];
        Wch[idx] = __float2half(s);
    }
    if (idx < OD) {
        float s = bf[idx];
        for (int k = 0; k < FD; k++) s += b2[k] * Wf[k * OD + idx];
        bc[idx] = s;
    }
}

// ---------------- launch ----------------
extern "C" void kernel_launch(void* const* d_in, const int* in_sizes, int n_in,
                              void* d_out, int out_size, void* d_ws, size_t ws_size,
                              hipStream_t stream) {
    const float* in_feat = (const float*)d_in[0];
    const int*   src     = (const int*)d_in[1];
    const int*   dst     = (const int*)d_in[2];
    const float* W1      = (const float*)d_in[3];
    const float* b1      = (const float*)d_in[4];
    const float* W2      = (const float*)d_in[5];
    const float* b2      = (const float*)d_in[6];
    const float* Wf      = (const float*)d_in[7];
    const float* bf      = (const float*)d_in[8];
    float* out = (float*)d_out;

    const int N = in_sizes[0] / FD;        // 50000
    const int E = in_sizes[1];             // 1600000
    const int NR = (N + RN - 1) / RN;      // 196 (<= NRMAX)
    const int CS = (((E + CHUNKS - 1) / CHUNKS) + 3) & ~3;  // 4-aligned for int4

    char* ws = (char*)d_ws;
    size_t off = 0;
    auto alloc = [&](size_t bytes) -> void* {
        void* p = ws + off;
        off += (bytes + 255) / 256 * 256;
        return p;
    };
    // spack (1.6 MB) + epack (6.4 MB) adjacent; both dead before gemm2 writes
    // tbuf (N*OD*2 = 6.4 MB) which aliases them.
    unsigned char* spack = (unsigned char*)alloc((size_t)E);
    int*    epack   = (int*)alloc((size_t)E * 4);
    __half* tbuf    = (__half*)spack;              // row-major [N][64]
    float*  r_out   = (float*)alloc((size_t)N * 4);
    float*  r_in    = (float*)alloc((size_t)N * 4);
    int*    hist_g  = (int*)alloc((size_t)CHUNKS * NRMAX * 4);
    int*    hist_gs = (int*)alloc((size_t)CHUNKS * NRMAX * 4);
    int*    cursor  = (int*)alloc((size_t)CHUNKS * NRMAX * 4);
    int*    scursor = (int*)alloc((size_t)CHUNKS * NRMAX * 4);
    int*    rstart  = (int*)alloc((size_t)(NR + 1) * 4);
    int*    sstart  = (int*)alloc((size_t)(NR + 1) * 4);
    int*    csrc    = (int*)alloc((size_t)E * 4);
    int*    row_start = (int*)alloc((size_t)(N + 1) * 4);
    __half* z1h     = (__half*)alloc((size_t)N * FD * 2);   // row-major [N][128]
    __half* y1h     = (__half*)alloc((size_t)N * FD * 2);   // row-major [N][128]
    __half* Xs      = (__half*)alloc((size_t)N * FD * 2);   // row-major [N][128]
    __half* W1h     = (__half*)alloc((size_t)FD * FD * 2);
    __half* Wch     = (__half*)alloc((size_t)FD * OD * 2);
    float*  bc      = (float*)alloc((size_t)OD * 4);
    (void)ws_size; (void)n_in; (void)out_size;

    const int ntiles = (N + 15) / 16;      // 3125
    const int gemmgrid = ntiles < 1024 ? ntiles : 1024;

    // exact dst-sort + src-degree count, zero per-edge global atomics:
    // dual region partition (pass 1) then per-region LDS passes (pass 2).
    region_hist_kernel<<<CHUNKS, 1024, 0, stream>>>(src, dst, hist_g, hist_gs, E, NR, CS);
    region_scan_kernel<<<1, 1024, 0, stream>>>(hist_g, hist_gs, rstart, cursor, sstart, scursor, NR, E);
    partition_kernel<<<CHUNKS, 1024, 0, stream>>>(src, dst, cursor, scursor, epack, spack, E, NR, CS);
    region_sort_kernel<<<NR, 1024, 0, stream>>>(epack, rstart, csrc, row_start, r_in, N, NR, E);
    rout2_kernel<<<NR, 256, 0, stream>>>(spack, sstart, r_out, N);

    // fold weights (fp16) + combined final bias
    fold_kernel<<<(FD * FD + 255) / 256, 256, 0, stream>>>(W2, Wf, b2, bf, W1, W1h, Wch, bc);

    // layer 1: Xs = half(r_out*x) ; z1h = half(r_in*Agg(Xs))
    prescale_kernel<<<(N * 32 + 255) / 256, 256, 0, stream>>>(in_feat, r_out, Xs, N * 32);
    agg128_kernel<<<(N + 3) / 4, 256, 0, stream>>>(Xs, r_in, row_start, csrc, z1h, N);

    // MFMA GEMMs: y1h = relu(z1h@W1h+b1)*r_out ; tbuf = y1h@Wch
    gemm1_mfma_kernel<<<gemmgrid, 256, 0, stream>>>(z1h, W1h, b1, r_out, y1h, N, ntiles);
    gemm2_mfma_kernel<<<gemmgrid, 256, 0, stream>>>(y1h, Wch, tbuf, N, ntiles);

    // final: out = r_in*Agg(tbuf) + bc
    agg64_kernel<<<(N + 7) / 8, 256, 0, stream>>>(tbuf, r_in, row_start, csrc, bc, out, N);
}